// Round 26
// baseline (26.036 us; speedup 1.0000x reference)
//
#include <hip/hip_runtime.h>
#include <math.h>

#define N      8192
#define BLK    256
#define RPT    16                   // resident b-points per lane
#define G      (RPT / 2)            // packed pair-groups per lane (8)
#define BPW    (64 * RPT)           // 1024 b-points per wave
#define NB     (N / BPW)            // 8 b-groups
#define NA     (N / 64)             // 128 a-tiles
#define GRID   ((NB * NA) / 4)      // 256 blocks of 4 waves (1 wave/SIMD)
#define RBLK   1024
#define RGRID  8                    // widened reduce: 8 blocks

typedef float v2f __attribute__((ext_vector_type(2)));

// Full-wave rotate-by-1 on the VALU pipe (DPP wave_ror:1, ctrl 0x13C).
__device__ __forceinline__ float rot1(float x) {
    return __int_as_float(__builtin_amdgcn_mov_dpp(
        __float_as_int(x), 0x13C, 0xF, 0xF, false));
}

__device__ __forceinline__ float min3f(float a, float b, float c) {
    return fminf(fminf(a, b), c);   // -> v_min3_f32
}

// ---------------------------------------------------- precompute + init ----
__global__ __launch_bounds__(BLK) void chamfer_prep_kernel(
        const float* __restrict__ tgt, const float* __restrict__ outp,
        float4* __restrict__ P, unsigned* __restrict__ dmin) {
    int i = blockIdx.x * BLK + (int)threadIdx.x;   // 0 .. 2N-1
    const float* src = (i < N) ? tgt : outp;
    int k = (i < N) ? i : (i - N);
    float x = src[3 * k + 0];
    float y = src[3 * k + 1];
    float z = src[3 * k + 2];
    P[i] = make_float4(x, y, z, fmaf(x, x, fmaf(y, y, z * z)));
    dmin[i] = 0x7F800000u;  // +inf
}

// ---------------------------------------------------------------- dist ----
// DPP systolic ring at RPT=16: 1024 wave-tasks (half of R25's 2048), each
// covering 2x the pairs. Rationale: the ~12us "fixed" cost has survived
// every lever and is suspected PER-WAVE phase cost (prologue loads, LDS
// init, commit, ramp/drain); halving wave count amortizes it 2x. Rotation
// cost per pair also halves (5 rots / 16 pairs). Row-min via packed v2f
// min-tree (depth 4) + one min3 fold (R25's win). Block's 4 waves share
// bt -> LDS pre-combine, one global col commit per b-point per block.
__global__ __launch_bounds__(BLK) void chamfer_dist_kernel(
        const float4* __restrict__ P, unsigned* __restrict__ dmin) {
    __shared__ unsigned cm[BPW];               // 1024 block-combined col-mins

    int tid  = (int)threadIdx.x;
    int lane = tid & 63;
    int W    = (int)blockIdx.x * 4 + (tid >> 6);   // global wave id (0..1023)
    int bt   = W >> 7;                             // b-group (shared by block)
    int at   = W & (NA - 1);                       // a-tile  (per wave)

    #pragma unroll
    for (int k = 0; k < BPW / BLK; ++k)
        cm[tid + k * BLK] = 0x7F800000u;

    // resident B-points (output cloud), packed as point-pairs
    v2f bx2[G], by2[G], bz2[G], b22[G], ca2[G];
    #pragma unroll
    for (int g = 0; g < G; ++g) {
        float4 u = P[N + bt * BPW + (2 * g)     * 64 + lane];
        float4 v = P[N + bt * BPW + (2 * g + 1) * 64 + lane];
        bx2[g] = (v2f){u.x, v.x};
        by2[g] = (v2f){u.y, v.y};
        bz2[g] = (v2f){u.z, v.z};
        b22[g] = (v2f){u.w, v.w};
        ca2[g] = (v2f){__builtin_inff(), __builtin_inff()};
    }

    // own A-packet (target cloud)
    float4 a = P[at * 64 + lane];
    float px = -2.0f * a.x;
    float py = -2.0f * a.y;
    float pz = -2.0f * a.z;
    float pw = a.w;                       // a^2
    float pr = __builtin_inff();          // traveling row-min (d^2)

    __syncthreads();                      // cm initialized

    for (int s = 0; s < 64; ++s) {
        v2f px2 = {px, px}, py2 = {py, py}, pz2 = {pz, pz}, pw2 = {pw, pw};
        v2f t[G];
        #pragma unroll
        for (int g = 0; g < G; ++g) {
            v2f u = __builtin_elementwise_fma(pz2, bz2[g], b22[g] + pw2);
            u     = __builtin_elementwise_fma(py2, by2[g], u);
            u     = __builtin_elementwise_fma(px2, bx2[g], u);   // full d^2
            ca2[g] = __builtin_elementwise_min(ca2[g], u);
            t[g] = u;
        }
        // packed min tree over the 16 candidates (depth 4), then fold pr
        v2f m01 = __builtin_elementwise_min(t[0], t[1]);
        v2f m23 = __builtin_elementwise_min(t[2], t[3]);
        v2f m45 = __builtin_elementwise_min(t[4], t[5]);
        v2f m67 = __builtin_elementwise_min(t[6], t[7]);
        v2f mA  = __builtin_elementwise_min(m01, m23);
        v2f mB  = __builtin_elementwise_min(m45, m67);
        v2f mT  = __builtin_elementwise_min(mA, mB);
        pr = min3f(mT.x, mT.y, pr);

        px = rot1(px);
        py = rot1(py);
        pz = rot1(pz);
        pw = rot1(pw);
        pr = rot1(pr);
    }

    // packet home after 64 rotations: commit row-min (per-wave a-tile)
    atomicMin(&dmin[at * 64 + lane], __float_as_uint(fmaxf(pr, 0.0f)));

    // col-mins: LDS pre-combine across the block's 4 waves, then ONE
    // global commit per b-point per block.
    #pragma unroll
    for (int g = 0; g < G; ++g) {
        atomicMin(&cm[(2 * g)     * 64 + lane],
                  __float_as_uint(fmaxf(ca2[g].x, 0.0f)));
        atomicMin(&cm[(2 * g + 1) * 64 + lane],
                  __float_as_uint(fmaxf(ca2[g].y, 0.0f)));
    }
    __syncthreads();
    #pragma unroll
    for (int k = 0; k < BPW / BLK; ++k)
        atomicMin(&dmin[N + bt * BPW + tid + k * BLK], cm[tid + k * BLK]);
}

// -------------------------------------------------------------- reduce ----
// 8 blocks x 1024 threads, each covering 1/8 of both dmin arrays.
__global__ __launch_bounds__(RBLK) void chamfer_reduce_kernel(
        const unsigned* __restrict__ dmin, float* __restrict__ bsum) {
    __shared__ float sh1[RBLK / 64], sh2[RBLK / 64];
    int t = (int)threadIdx.x;
    int chunk = N / 4 / RGRID;                     // uint4 elems per block
    int base = (int)blockIdx.x * chunk;
    float s1 = 0.0f, s2 = 0.0f;
    const uint4* da = (const uint4*)dmin;          // dist1 as uint4
    const uint4* db = (const uint4*)(dmin + N);    // dist2 as uint4
    for (int i = t; i < chunk; i += RBLK) {
        uint4 v1 = da[base + i], v2 = db[base + i];
        s1 += sqrtf(__uint_as_float(v1.x)) + sqrtf(__uint_as_float(v1.y))
            + sqrtf(__uint_as_float(v1.z)) + sqrtf(__uint_as_float(v1.w));
        s2 += sqrtf(__uint_as_float(v2.x)) + sqrtf(__uint_as_float(v2.y))
            + sqrtf(__uint_as_float(v2.z)) + sqrtf(__uint_as_float(v2.w));
    }
    #pragma unroll
    for (int off = 32; off > 0; off >>= 1) {
        s1 += __shfl_down(s1, off, 64);
        s2 += __shfl_down(s2, off, 64);
    }
    int wid = t >> 6, lane = t & 63;
    if (lane == 0) { sh1[wid] = s1; sh2[wid] = s2; }
    __syncthreads();
    if (t == 0) {
        float t1 = 0.0f, t2 = 0.0f;
        #pragma unroll
        for (int w = 0; w < RBLK / 64; ++w) { t1 += sh1[w]; t2 += sh2[w]; }
        bsum[blockIdx.x]         = t1;
        bsum[RGRID + blockIdx.x] = t2;
    }
}

// ----------------------------------------------------------------- final ----
__global__ void chamfer_final_kernel(const float* __restrict__ bsum,
        const int* __restrict__ curp, const int* __restrict__ subp,
        float* __restrict__ out) {
    if (threadIdx.x != 0) return;
    float s1 = 0.0f, s2 = 0.0f;
    #pragma unroll
    for (int b = 0; b < RGRID; ++b) { s1 += bsum[b]; s2 += bsum[RGRID + b]; }
    int e = curp[0] / subp[0];
    double scale = 10.0 / pow(0.99, (double)e);
    out[0] = (float)((((double)s1 + (double)s2) / (double)N) * 0.5 * scale);
}

// ---------------------------------------------------------------- launch ----
extern "C" void kernel_launch(void* const* d_in, const int* in_sizes, int n_in,
                              void* d_out, int out_size, void* d_ws, size_t ws_size,
                              hipStream_t stream) {
    const float* target = (const float*)d_in[0];   // (1, 8192, 3) f32
    const float* output = (const float*)d_in[1];   // (1, 8192, 3) f32
    const int*   curp   = (const int*)d_in[2];
    const int*   subp   = (const int*)d_in[3];
    float* out = (float*)d_out;

    // ws: float4 P[2N] (256KB) | uint dmin[2N] (64KB) | float bsum[16]
    float4*   P    = (float4*)d_ws;
    unsigned* dmin = (unsigned*)(P + 2 * N);
    float*    bsum = (float*)(dmin + 2 * N);

    chamfer_prep_kernel<<<2 * N / BLK, BLK, 0, stream>>>(target, output, P, dmin);
    chamfer_dist_kernel<<<GRID, BLK, 0, stream>>>(P, dmin);
    chamfer_reduce_kernel<<<RGRID, RBLK, 0, stream>>>(dmin, bsum);
    chamfer_final_kernel<<<1, 64, 0, stream>>>(bsum, curp, subp, out);
}